// Round 4
// baseline (322.569 us; speedup 1.0000x reference)
//
#include <hip/hip_runtime.h>
#include <math.h>

typedef __bf16 bf16;
typedef __attribute__((ext_vector_type(8))) __bf16 bf16x8;
typedef __attribute__((ext_vector_type(4))) float f32x4;

// ---------------------------------------------------------------------------
// B=16, L=1024, U=512, H=2. M = 16384. fp32 I/O, bf16 internal.
// R14: R13 + fix — fused attn was missing the cross-wave lsum reduction
// (each wave only summed its own 32-col slice). Added LDS reduction across
// the 4 wc waves before normalizing.
// ---------------------------------------------------------------------------

__device__ __forceinline__ void load_lds16(const bf16* g, bf16* l) {
  __builtin_amdgcn_global_load_lds(
      (const __attribute__((address_space(1))) unsigned int*)(g),
      (__attribute__((address_space(3))) unsigned int*)(l), 16, 0, 0);
}

// ===================== dual-column fused-gating GEMM =======================
// (R0-proven 128x128 tile, 4 waves 2x2, BK=64, granule-XOR swizzle, 0 bank
// conflicts, 4 blocks/CU.)
struct DualArgs {
  const bf16* A; const bf16* A2;   // A2 = rows for k>=512 (final); else == A
  const bf16* Bt;
  void* C; const void* xres;
  const float* bias_t; const float* bias_c;
  int K, ldb;
  const float* aW;                 // EPI 2
  float* s1a; float* s2a;          // EPI 2: atomic partial dots
  bf16* q;                         // EPI 2: x * w3
  bf16* xT;                        // EPI 2: per-batch transpose of x2
};

template<int EPI>  // 0 = highway, 2 = highway + s1/s2/q/xT fusion, 1 = final
__global__ __launch_bounds__(256, 4)
void gemm_dual(DualArgs g) {
  __shared__ bf16 smem[2 * 128 * 64];      // As | Bs; reused as Ts in EPI 2
  bf16* As = smem;
  bf16* Bs = smem + 8192;
  const int tid = threadIdx.x;
  const int bid = blockIdx.x;
  const int xcd = bid & 7;
  const int t = bid >> 3;
  const int bx = t & 7;
  const int r  = t >> 3;
  const int Rx = gridDim.x >> 6;
  const int by = xcd * Rx + r;

  const int wid = tid >> 6, lane = tid & 63;
  const int wm = (wid >> 1) << 6;
  const int wn = (wid & 1) << 6;
  const int lr = lane & 15, lq = lane >> 4;

  f32x4 acc[4][4];
#pragma unroll
  for (int i = 0; i < 4; i++)
#pragma unroll
    for (int j = 0; j < 4; j++) acc[i][j] = f32x4{0.f, 0.f, 0.f, 0.f};

  const int srow8 = (tid >> 3) & 7;
  const int skc   = (tid & 7) ^ srow8;
  const int lswz  = (lr & 7);
  const long long abase = (long long)(by * 128) * 512;

  for (int k0 = 0; k0 < g.K; k0 += 64) {
    const bf16* Ak = (k0 < 512) ? g.A : g.A2;
    const int kk = k0 & 511;
    __syncthreads();
#pragma unroll
    for (int j = 0; j < 4; j++) {
      const int ci = (tid >> 6) * 4 + j;
      const int bn = ci * 8 + srow8;
      load_lds16(Ak + abase + (long long)bn * 512 + kk + skc * 8, As + ci * 512);
      const int grp = bn >> 5, r5 = bn & 31;
      const int grow = ((grp & 1) << 9) + bx * 64 + ((grp >> 1) << 5) + r5;
      load_lds16(g.Bt + (long long)grow * g.ldb + k0 + skc * 8, Bs + ci * 512);
    }
    __syncthreads();
#pragma unroll
    for (int ks = 0; ks < 2; ks++) {
      bf16x8 af[4], bfr[4];
      const int kx = (ks * 4 + lq) ^ lswz;
#pragma unroll
      for (int i = 0; i < 4; i++)
        af[i] = *(const bf16x8*)(&As[(wm + i * 16 + lr) * 64 + kx * 8]);
#pragma unroll
      for (int j = 0; j < 4; j++)
        bfr[j] = *(const bf16x8*)(&Bs[(wn + j * 16 + lr) * 64 + kx * 8]);
#pragma unroll
      for (int i = 0; i < 4; i++)
#pragma unroll
        for (int j = 0; j < 4; j++)
          acc[i][j] = __builtin_amdgcn_mfma_f32_16x16x32_bf16(af[i], bfr[j], acc[i][j], 0, 0, 0);
    }
  }

  const int colb = bx * 64 + (wn >> 1);
  bf16 xn_arr[4][4][2];
#pragma unroll
  for (int i = 0; i < 4; i++) {
#pragma unroll
    for (int v = 0; v < 4; v++) {
      int row = by * 128 + wm + i * 16 + lq * 4 + v;
      float p1s = 0.f, p2s = 0.f;
#pragma unroll
      for (int j = 0; j < 2; j++) {
        int col = colb + j * 16 + lr;
        long long idx = (long long)row * 512 + col;
        float p0 = acc[i][j][v] + g.bias_t[col];
        float p1 = acc[i][j + 2][v] + g.bias_c[col];
        if (EPI == 1) {
          float z = 1.f / (1.f + __expf(-p0));
          float rr = 1.f / (1.f + __expf(-p1));
          float x = (float)((const bf16*)g.xres)[idx];   // bf16 residual
          ((float*)g.C)[idx] = rr * x + z * z;
        } else {
          float tt = fmaxf(p0, 0.f);
          float c = 1.f / (1.f + __expf(-p1));
          float x = (float)((const bf16*)g.xres)[idx];
          bf16 xn = (bf16)(tt * c + x * (1.f - c));
          ((bf16*)g.C)[idx] = xn;
          if (EPI == 2) {
            xn_arr[i][v][j] = xn;
            float xf = (float)xn;
            p1s += xf * g.aW[col];
            p2s += xf * g.aW[512 + col];
            g.q[idx] = (bf16)(xf * g.aW[1024 + col]);
          }
        }
      }
      if (EPI == 2) {
        p1s += __shfl_xor(p1s, 1, 64);
        p1s += __shfl_xor(p1s, 2, 64);
        p1s += __shfl_xor(p1s, 4, 64);
        p1s += __shfl_xor(p1s, 8, 64);
        p2s += __shfl_xor(p2s, 1, 64);
        p2s += __shfl_xor(p2s, 2, 64);
        p2s += __shfl_xor(p2s, 4, 64);
        p2s += __shfl_xor(p2s, 8, 64);
        if (lr == 0) {
          atomicAdd(&g.s1a[row], p1s);
          atomicAdd(&g.s2a[row], p2s);
        }
      }
    }
  }

  if (EPI == 2) {
    // fused transpose: 128x64 tile of x2 -> LDS (stride 136) -> coalesced xT
    bf16* Ts = smem;
    __syncthreads();
#pragma unroll
    for (int i = 0; i < 4; i++)
#pragma unroll
      for (int v = 0; v < 4; v++)
#pragma unroll
        for (int j = 0; j < 2; j++) {
          int rloc = wm + i * 16 + lq * 4 + v;
          int cloc = (wn >> 1) + j * 16 + lr;
          Ts[cloc * 136 + rloc] = xn_arr[i][v][j];
        }
    __syncthreads();
    const int b = by >> 3;
    bf16* dst = g.xT + (long long)b * 524288 + ((by & 7) * 128);
#pragma unroll
    for (int it = 0; it < 2; it++) {
      int d = (tid >> 3) + it * 32;
      int jb = (tid & 7) * 16;
      bf16x8 v0 = *(const bf16x8*)(&Ts[d * 136 + jb]);
      bf16x8 v1 = *(const bf16x8*)(&Ts[d * 136 + jb + 8]);
      long long o = (long long)(bx * 64 + d) * 1024 + jb;
      *(bf16x8*)(dst + o) = v0;
      *(bf16x8*)(dst + o + 8) = v1;
    }
  }
}

// ======================= fused flash scores + PV ===========================
// Per block: 64 Q-rows (256 blocks = 16 batch x 16 tiles), 512 thr, 8 waves
// (wr 2 x wc 4). Q in LDS once (64KB, granule-swizzled). Loop 8 KV-tiles of
// 128: QK^T (dbuf Bs 16KB x2) -> E=exp(relu clamp) + running row-sums ->
// E-tile to swizzled LDS (16KB) -> PV MFMA, B-frags direct from L2-hot xT16.
// E never touches HBM; no lsum atomics. lsum reduced across wc waves via LDS.
struct AttnArgs {
  const bf16* Q;     // q16 [16][1024][512]
  const bf16* X;     // x2  [16][1024][512]
  const bf16* XT;    // xT16[16][512][1024]
  bf16* O;           // att16 [16][1024][512]
  const float* s1; const float* s2; const float* abp;
};

__global__ __launch_bounds__(512, 2)
void attn_fused(AttnArgs g) {
  // Qs [0,32768) | Bs dbuf [32768,49152) | Es [49152,57344)
  __shared__ __align__(16) bf16 smem[57344];
  __shared__ float lsum_sh[4][64];
  bf16* Qs = smem;
  bf16* Es = smem + 49152;
  const int tid = threadIdx.x;
  const int bid = blockIdx.x;
  const int gr = (bid & 7) * 32 + (bid >> 3);   // XCD-contiguous batches
  const int bz = gr >> 4, qt = gr & 15;
  const int wid = tid >> 6, lane = tid & 63;
  const int wr = wid >> 2, wc = wid & 3;
  const int lr = lane & 15, lq = lane >> 4;
  const int lswz = lr & 7;
  const int srow8 = (lane >> 3) & 7;
  const int skc = (lane & 7) ^ srow8;

  const bf16* Qg = g.Q + (long long)bz * 524288 + (long long)(qt * 64) * 512;
  const bf16* Xg = g.X + (long long)bz * 524288;
  const bf16* XTg = g.XT + (long long)bz * 524288;

  // stage Q fully: wave wid stages k-panel wid (chunks = 8 rows x 64 k)
#pragma unroll
  for (int c8 = 0; c8 < 8; c8++) {
    const int row = c8 * 8 + srow8;
    load_lds16(Qg + (long long)row * 512 + wid * 64 + skc * 8,
               Qs + (wid * 8 + c8) * 512);
  }
  // stage Bs(jt=0, p=0) into buf 0
#pragma unroll
  for (int jj = 0; jj < 2; jj++) {
    const int c = wid * 2 + jj;
    load_lds16(Xg + (long long)(c * 8 + srow8) * 512 + skc * 8,
               smem + 32768 + c * 512);
  }

  // per-row constants and accumulators
  float s1r[2][4];
#pragma unroll
  for (int i = 0; i < 2; i++)
#pragma unroll
    for (int v = 0; v < 4; v++)
      s1r[i][v] = g.s1[bz * 1024 + qt * 64 + wr * 32 + i * 16 + lq * 4 + v] + g.abp[0];

  f32x4 acc_o[2][8];
  float lsum[2][4];
#pragma unroll
  for (int i = 0; i < 2; i++) {
#pragma unroll
    for (int jd = 0; jd < 8; jd++) acc_o[i][jd] = f32x4{0.f, 0.f, 0.f, 0.f};
#pragma unroll
    for (int v = 0; v < 4; v++) lsum[i][v] = 0.f;
  }

  __syncthreads();

  int cur = 0;
  for (int jt = 0; jt < 8; jt++) {
    // -------- QK^T over K=512, dbuf Bs --------
    f32x4 acc_s[2][2];
#pragma unroll
    for (int i = 0; i < 2; i++)
#pragma unroll
      for (int jjf = 0; jjf < 2; jjf++) acc_s[i][jjf] = f32x4{0.f, 0.f, 0.f, 0.f};

    for (int p = 0; p < 8; p++) {
      // stage next panel (or next j-tile's p0) into the other buffer
      if (p < 7) {
#pragma unroll
        for (int jj = 0; jj < 2; jj++) {
          const int c = wid * 2 + jj;
          load_lds16(Xg + (long long)(jt * 128 + c * 8 + srow8) * 512 + (p + 1) * 64 + skc * 8,
                     smem + 32768 + (cur ^ 1) * 8192 + c * 512);
        }
      } else if (jt + 1 < 8) {
#pragma unroll
        for (int jj = 0; jj < 2; jj++) {
          const int c = wid * 2 + jj;
          load_lds16(Xg + (long long)((jt + 1) * 128 + c * 8 + srow8) * 512 + skc * 8,
                     smem + 32768 + (cur ^ 1) * 8192 + c * 512);
        }
      }
      bf16x8 aq[2][2], bx[2][2];
#pragma unroll
      for (int ks = 0; ks < 2; ks++) {
        const int kx = (ks * 4 + lq) ^ lswz;
#pragma unroll
        for (int i = 0; i < 2; i++)
          aq[i][ks] = *(const bf16x8*)(&Qs[p * 4096 + (wr * 32 + i * 16 + lr) * 64 + kx * 8]);
#pragma unroll
        for (int jjf = 0; jjf < 2; jjf++)
          bx[jjf][ks] = *(const bf16x8*)(&smem[32768 + cur * 8192 + (wc * 32 + jjf * 16 + lr) * 64 + kx * 8]);
      }
#pragma unroll
      for (int i = 0; i < 2; i++)
#pragma unroll
        for (int jjf = 0; jjf < 2; jjf++)
#pragma unroll
          for (int ks = 0; ks < 2; ks++)
            acc_s[i][jjf] = __builtin_amdgcn_mfma_f32_16x16x32_bf16(aq[i][ks], bx[jjf][ks], acc_s[i][jjf], 0, 0, 0);
      __syncthreads();
      cur ^= 1;
    }

    // -------- E = exp(clamp(relu(S + s1 + s2 + ab))), row-sums, E -> LDS ----
    float s2v[2];
#pragma unroll
    for (int jjf = 0; jjf < 2; jjf++)
      s2v[jjf] = g.s2[bz * 1024 + jt * 128 + wc * 32 + jjf * 16 + lr];
#pragma unroll
    for (int i = 0; i < 2; i++) {
#pragma unroll
      for (int v = 0; v < 4; v++) {
        const int rl = wr * 32 + i * 16 + lq * 4 + v;
        float ps = 0.f;
#pragma unroll
        for (int jjf = 0; jjf < 2; jjf++) {
          const int jl = wc * 32 + jjf * 16 + lr;
          float val = acc_s[i][jjf][v] + s1r[i][v] + s2v[jjf];
          val = fminf(fmaxf(val, 0.f), 60.f);
          val = __expf(val);
          bf16 eb = (bf16)val;
          ps += (float)eb;
          Es[(jl >> 6) * 4096 + rl * 64 + (((jl >> 3) & 7) ^ (rl & 7)) * 8 + (jl & 7)] = eb;
        }
        ps += __shfl_xor(ps, 1, 64);
        ps += __shfl_xor(ps, 2, 64);
        ps += __shfl_xor(ps, 4, 64);
        ps += __shfl_xor(ps, 8, 64);
        lsum[i][v] += ps;
      }
    }
    __syncthreads();   // Es visible to all waves

    // -------- PV: acc_o += E(64x128) @ x2_j(128x512), B from global xT ------
#pragma unroll
    for (int kq = 0; kq < 4; kq++) {
      bf16x8 aE[2];
      const int kx = (((kq & 1) * 4 + lq)) ^ lswz;
#pragma unroll
      for (int i = 0; i < 2; i++)
        aE[i] = *(const bf16x8*)(&Es[(kq >> 1) * 4096 + (wr * 32 + i * 16 + lr) * 64 + kx * 8]);
      bf16x8 bv[8];
#pragma unroll
      for (int jd = 0; jd < 8; jd++)
        bv[jd] = *(const bf16x8*)(XTg + (long long)(wc * 128 + jd * 16 + lr) * 1024
                                  + jt * 128 + kq * 32 + lq * 8);
#pragma unroll
      for (int jd = 0; jd < 8; jd++) {
        acc_o[0][jd] = __builtin_amdgcn_mfma_f32_16x16x32_bf16(aE[0], bv[jd], acc_o[0][jd], 0, 0, 0);
        acc_o[1][jd] = __builtin_amdgcn_mfma_f32_16x16x32_bf16(aE[1], bv[jd], acc_o[1][jd], 0, 0, 0);
      }
    }
    // next k-loop's first read (Bs[cur] = next j-tile p0) was staged+synced
  }

  // ------- cross-wave lsum reduction (4 wc waves share each wr) -----------
  if (lr == 0) {
#pragma unroll
    for (int i = 0; i < 2; i++)
#pragma unroll
      for (int v = 0; v < 4; v++)
        lsum_sh[wc][wr * 32 + i * 16 + lq * 4 + v] = lsum[i][v];
  }
  __syncthreads();

  // ---------------- epilogue: att = acc_o / lsum, coalesced stores ---------
  bf16* Ts = smem;                 // 64 x 520 (stride breaks bank pattern)
  float rinv[2][4];
#pragma unroll
  for (int i = 0; i < 2; i++)
#pragma unroll
    for (int v = 0; v < 4; v++) {
      const int rl = wr * 32 + i * 16 + lq * 4 + v;
      const float tot = lsum_sh[0][rl] + lsum_sh[1][rl] + lsum_sh[2][rl] + lsum_sh[3][rl];
      rinv[i][v] = 1.f / tot;
    }
  __syncthreads();
#pragma unroll
  for (int i = 0; i < 2; i++)
#pragma unroll
    for (int jd = 0; jd < 8; jd++)
#pragma unroll
      for (int v = 0; v < 4; v++) {
        const int rl = wr * 32 + i * 16 + lq * 4 + v;
        const int d = wc * 128 + jd * 16 + lr;
        Ts[rl * 520 + d] = (bf16)(acc_o[i][jd][v] * rinv[i][v]);
      }
  __syncthreads();
  bf16* Og = g.O + (long long)bz * 524288 + (long long)(qt * 64) * 512;
#pragma unroll
  for (int rr = 0; rr < 8; rr++) {
    const int row = wid * 8 + rr;
    bf16x8 vv = *(const bf16x8*)(&Ts[row * 520 + lane * 8]);
    *(bf16x8*)(Og + (long long)row * 512 + lane * 8) = vv;
  }
}

// ============================ prep kernel ==================================
__device__ __forceinline__ void tile_transpose(const float* src, int sld,
                                               bf16* dst, int dld,
                                               int k0, int n0, int tid) {
  __shared__ float tile[64][65];
  const int rr = tid >> 4, c4 = (tid & 15) * 4;
#pragma unroll
  for (int it = 0; it < 4; it++) {
    int r = rr + it * 16;
    f32x4 v = *(const f32x4*)(src + (long long)(k0 + r) * sld + n0 + c4);
    tile[r][c4] = v[0]; tile[r][c4 + 1] = v[1];
    tile[r][c4 + 2] = v[2]; tile[r][c4 + 3] = v[3];
  }
  __syncthreads();
  const int nl = tid >> 2, kb = (tid & 3) * 16;
  bf16x8 o0, o1;
#pragma unroll
  for (int kk = 0; kk < 8; kk++) o0[kk] = (bf16)tile[kb + kk][nl];
#pragma unroll
  for (int kk = 0; kk < 8; kk++) o1[kk] = (bf16)tile[kb + 8 + kk][nl];
  bf16* d = dst + (long long)(n0 + nl) * dld + k0 + kb;
  *(bf16x8*)d = o0;
  *(bf16x8*)(d + 8) = o1;
}

__global__ void prep(const float* tW, const float* tb, const float* cW, const float* cb,
                     const float* frW, const float* frb, const float* ffW, const float* ffb,
                     const float* inp, bf16* xb0,
                     bf16* w1T, bf16* w2T, float* bias1, float* bias2, float* sred) {
  const int bid = blockIdx.x, tid = threadIdx.x;
  if (bid < 256) {
    const int quad = bid >> 6, tile = bid & 63;
    const int l = quad >> 1, half = quad & 1;
    const float* src = (half ? cW : tW) + l * 262144;
    bf16* dst = w1T + l * 524288 + half * 262144;
    tile_transpose(src, 512, dst, 512, (tile >> 3) * 64, (tile & 7) * 64, tid);
  } else if (bid < 512) {
    const int j = bid - 256;
    const int half = j >> 7, tile = j & 127;
    const float* src = half ? frW : ffW;
    bf16* dst = w2T + half * 524288;
    tile_transpose(src, 512, dst, 1024, (tile >> 3) * 64, (tile & 7) * 64, tid);
  } else if (bid < 4608) {
    long long i8 = (((long long)(bid - 512)) * 256 + tid) * 8;
    bf16x8 o;
#pragma unroll
    for (int k = 0; k < 8; k++) o[k] = (bf16)inp[i8 + k];
    *(bf16x8*)(xb0 + i8) = o;
  } else {
    for (int j = tid; j < 3072; j += 256) {
      if (j < 2048) {
        int l = j >> 10, n = j & 1023;
        bias1[j] = (n < 512) ? tb[l * 512 + n] : cb[l * 512 + (n - 512)];
      } else {
        int n = j - 2048;
        bias2[n] = (n < 512) ? ffb[n] : frb[n - 512];
      }
    }
    for (int j = tid; j < 12288; j += 256)
      *(f32x4*)(sred + j * 4) = f32x4{0.f, 0.f, 0.f, 0.f};
  }
}

extern "C" void kernel_launch(void* const* d_in, const int* in_sizes, int n_in,
                              void* d_out, int out_size, void* d_ws, size_t ws_size,
                              hipStream_t stream) {
  const float* inp = (const float*)d_in[0];
  const float* tW  = (const float*)d_in[1];
  const float* tb  = (const float*)d_in[2];
  const float* cW  = (const float*)d_in[3];
  const float* cb  = (const float*)d_in[4];
  const float* aW  = (const float*)d_in[5];
  const float* ab  = (const float*)d_in[6];
  const float* frW = (const float*)d_in[7];
  const float* frb = (const float*)d_in[8];
  const float* ffW = (const float*)d_in[9];
  const float* ffb = (const float*)d_in[10];
  float* out = (float*)d_out;

  char* p = (char*)d_ws;
  auto alloc = [&](size_t bytes) { char* r = p; p += (bytes + 255) & ~size_t(255); return r; };
  bf16* xb0   = (bf16*) alloc(16777216);
  bf16* x1    = (bf16*) alloc(16777216);
  bf16* x2    = (bf16*) alloc(16777216);
  bf16* q16   = (bf16*) alloc(16777216);
  bf16* xT16  = (bf16*) alloc(16777216);
  bf16* att16 = (bf16*) alloc(16777216);
  float* sred = (float*)alloc(196608);     // s1 | s2 | (spare)
  bf16* w1T   = (bf16*) alloc(2097152);
  bf16* w2T   = (bf16*) alloc(2097152);
  float* bias1= (float*)alloc(8192);
  float* bias2= (float*)alloc(4096);
  float* s1 = sred, *s2 = sred + 16384;

  prep<<<4609, 256, 0, stream>>>(
      tW, tb, cW, cb, frW, frb, ffW, ffb, inp, xb0, w1T, w2T, bias1, bias2, sred);

  {  // highway 1
    DualArgs g{};
    g.A = xb0; g.A2 = xb0; g.Bt = w1T;
    g.C = x1; g.xres = xb0;
    g.bias_t = bias1; g.bias_c = bias1 + 512;
    g.K = 512; g.ldb = 512;
    gemm_dual<0><<<1024, 256, 0, stream>>>(g);
  }
  {  // highway 2 + fused s1/s2/q + fused transpose
    DualArgs g{};
    g.A = x1; g.A2 = x1; g.Bt = w1T + 524288;
    g.C = x2; g.xres = x1;
    g.bias_t = bias1 + 1024; g.bias_c = bias1 + 1536;
    g.K = 512; g.ldb = 512;
    g.aW = aW; g.s1a = s1; g.s2a = s2; g.q = q16; g.xT = xT16;
    gemm_dual<2><<<1024, 256, 0, stream>>>(g);
  }
  {  // fused flash: att = softmax-ish(QK^T + s1 + s2 + ab) @ x2
    AttnArgs g{};
    g.Q = q16; g.X = x2; g.XT = xT16; g.O = att16;
    g.s1 = s1; g.s2 = s2; g.abp = ab;
    attn_fused<<<256, 512, 0, stream>>>(g);
  }
  {  // final: out = r*x + z*z, z/r = sigmoid([xb0|att] @ [ffW|frW] + b)
    DualArgs g{};
    g.A = xb0; g.A2 = att16; g.Bt = w2T;
    g.C = out; g.xres = xb0;               // bf16 residual
    g.bias_t = bias2; g.bias_c = bias2 + 512;
    g.K = 1024; g.ldb = 1024;
    gemm_dual<1><<<1024, 256, 0, stream>>>(g);
  }
}